// Round 8
// baseline (5562.598 us; speedup 1.0000x reference)
//
#include <hip/hip_runtime.h>

// LSTMBaseline: B=2048, T=512, H=128, 4H=512, FF=64, OUT=2 ; fp32 in/out.
// R17 = R16 design (8 waves / 2 per SIMD, 160 AGPR resident weights, only
// whh1 kt2-3 streamed from a 64KB LDS wtab) with the R13-class hazard fixed.
// R16 failure diagnosis: the gbuf handoff writes are guarded `if (kg<2)`, so
// per-THREAD alias analysis sees no dependence between a thread's ds_reads
// (rows kg, kg+4) and the wave's ds_writes (rows 4kg..4kg+3) for most lanes;
// LLVM may hoist the reads above the writes at IR level (sched_barrier(0)
// only pins the machine scheduler). R9 passing with this pattern was
// schedule luck. Fixes:
//  (1) handoff via VOLATILE LDS accesses (wave-synchronous discipline):
//      volatile keeps write->read program order at IR level; LDS is in-order
//      per wave at HW level. sched_barrier(0) kept as machine-level pin.
//  (2) gA/gB split per phase (R10-validated): no cross-phase WAR subtlety.
//  (3) biases + wih0 row moved to LDS tables (R14-validated): arch regs
//      ~92 + 160 AGPR = 252 <= 256 -> zero in-loop spill (watch WRITE_SIZE).
// Design recap (why this should beat R9's 1163us):
//  - R9 spilled ~64 regs/wave -> ~2300 cyc/step/CU of scratch reloads. Gone.
//  - whh0(64) + wih1(64) + whh1 kt0-1(32) AGPR-pinned; whh1 kt2-3 (8 frags,
//    128B/thread/step) streamed from wtab, prefetched under 16+ MFMAs.
//  - cell math: R9's all-lane 2-unit form (non-divergent), prescaled weights
//    (log2e; 2x for g-gate), biases folded into MFMA acc init, v_exp_f32.

#define TT 512
#define HH 128
#define FFD 64
#define BB 8
#define NT 512   // 8 waves, 2 per SIMD
#define HP 136   // padded LDS row stride (ushort); 272B = 16B-aligned rows

typedef __attribute__((ext_vector_type(8))) short short8;
typedef __attribute__((ext_vector_type(4))) float f32x4;

#define L2E  1.4426950408889634f
#define L2E2 2.8853900817779268f

__device__ __forceinline__ unsigned short f2b(float f) {
    unsigned int i = __builtin_bit_cast(unsigned int, f);
    i += 0x7FFFu + ((i >> 16) & 1u);   // RNE
    return (unsigned short)(i >> 16);
}
__device__ __forceinline__ float b2f(unsigned short u) {
    return __builtin_bit_cast(float, ((unsigned int)u) << 16);
}
__device__ __forceinline__ float fexp2(float x) {
#if __has_builtin(__builtin_amdgcn_exp2f)
    return __builtin_amdgcn_exp2f(x);     // v_exp_f32
#else
    return exp2f(x);
#endif
}
__device__ __forceinline__ float frcp(float x) {
#if __has_builtin(__builtin_amdgcn_rcpf)
    return __builtin_amdgcn_rcpf(x);      // v_rcp_f32
#else
    return 1.0f / x;
#endif
}
// pre-scaled activations: y already multiplied by log2e (sigm) / 2*log2e (tanh)
__device__ __forceinline__ float sigm_s(float y) {
    return frcp(1.0f + fexp2(-y));
}
__device__ __forceinline__ float tanh_s(float y) {
    return 1.0f - 2.0f * frcp(1.0f + fexp2(y));
}
// natural-domain tanh (for cell state c)
__device__ __forceinline__ float tanh_c(float x) {
    return 1.0f - 2.0f * frcp(1.0f + fexp2(L2E2 * x));
}
// 8 consecutive fp32 -> bf16 short8 fragment, scaled
__device__ __forceinline__ short8 ldfrag(const float* p, unsigned idx, float s) {
    const float4* q = reinterpret_cast<const float4*>(p + idx);
    float4 a = q[0], b = q[1];
    short8 r;
    r[0] = (short)f2b(a.x * s); r[1] = (short)f2b(a.y * s);
    r[2] = (short)f2b(a.z * s); r[3] = (short)f2b(a.w * s);
    r[4] = (short)f2b(b.x * s); r[5] = (short)f2b(b.y * s);
    r[6] = (short)f2b(b.z * s); r[7] = (short)f2b(b.w * s);
    return r;
}

#define MFMA(a, b, c) __builtin_amdgcn_mfma_f32_16x16x32_bf16((a), (b), (c), 0, 0, 0)

__global__ __launch_bounds__(NT, 2) void lstm2_fused(
    const float* __restrict__ hr,
    const float* __restrict__ glu,
    const float* __restrict__ wih0,
    const float* __restrict__ whh0,
    const float* __restrict__ bih0,
    const float* __restrict__ bhh0,
    const float* __restrict__ wih1,
    const float* __restrict__ whh1,
    const float* __restrict__ bih1,
    const float* __restrict__ bhh1,
    const float* __restrict__ w1,
    const float* __restrict__ b1,
    const float* __restrict__ w2,
    const float* __restrict__ b2,
    float* __restrict__ out)
{
    // h(t) lives in buffer t&1. Rows 8..15 stay zero (MFMA M=16 padding).
    __shared__ __align__(16) unsigned short h0b[2][16][HP];
    __shared__ __align__(16) unsigned short h1b[2][16][HP];
    __shared__ float gA[8][4][8][16];            // MM0->cell0 handoff (volatile access)
    __shared__ float gB[8][4][8][16];            // MM1->cell1 handoff (volatile access)
    __shared__ __align__(16) short8 wtab[8][NT]; // whh1 kt2-3 frags [(kt-2)*4+g][tid]
    __shared__ __align__(16) float b0t[HH][4];   // scaled bias0 [col][g]
    __shared__ __align__(16) float b1t[HH][4];   // scaled bias1 [col][g]
    __shared__ __align__(16) float wab[HH][8];   // scaled wih0 [col][{wa,wb}x4g]
    __shared__ float hid[BB][FFD];

    const int tid  = threadIdx.x;
    const int lane = tid & 63;
    const int wv   = tid >> 6;        // 0..7
    const int nrow = lane & 15;       // MFMA m (A) / n (B) index
    const int kg   = lane >> 4;       // MFMA k-group 0..3
    const int b0   = blockIdx.x * BB;

    // ---- init h buffers + const tables ----
    {
        unsigned short* p0 = &h0b[0][0][0];
        unsigned short* p1 = &h1b[0][0][0];
        for (int i = tid; i < 2 * 16 * HP; i += NT) { p0[i] = 0; p1[i] = 0; }
        {
            int i  = tid;                  // i = 128g + col, NT==512 covers all
            int g  = i >> 7;
            int jc = i & (HH - 1);
            float s = (g == 2) ? L2E2 : L2E;
            b0t[jc][g] = (bih0[i] + bhh0[i]) * s;
            b1t[jc][g] = (bih1[i] + bhh1[i]) * s;
            wab[jc][2 * g]     = wih0[2 * i] * s;
            wab[jc][2 * g + 1] = wih0[2 * i + 1] * s;
        }
    }

    // ---- wtab: whh1 kt 2-3 -> pre-scaled bf16 frags in LDS (streamed) ----
    // B-frag 16x16x32: lane(n=lane&15, q=lane>>4) holds B[k=32kt+8q+e][n]=W[col][k]
#pragma unroll
    for (int g = 0; g < 4; g++) {
        const float s = (g == 2) ? L2E2 : L2E;
        unsigned gc = (unsigned)(128 * g + 16 * wv + nrow);
#pragma unroll
        for (int kt = 2; kt < 4; kt++)
            wtab[(kt - 2) * 4 + g][tid] = ldfrag(whh1, gc * HH + kt * 32 + kg * 8, s);
    }

    // ---- resident frags: whh0(16) + wih1(16) + whh1 kt0-1(8) = 160 regs ----
    short8 W0f[4][4];   // [g][kt] whh0
    short8 Wi1[4][4];   // [g][kt] wih1
    short8 Whr[4][2];   // [g][kt] whh1 kt 0-1
#pragma unroll
    for (int g = 0; g < 4; g++) {
        const float s = (g == 2) ? L2E2 : L2E;
        unsigned gc = (unsigned)(128 * g + 16 * wv + nrow);
#pragma unroll
        for (int kt = 0; kt < 4; kt++) {
            unsigned off = gc * HH + kt * 32 + kg * 8;
            W0f[g][kt] = ldfrag(whh0, off, s);
            asm volatile("" : "+a"(W0f[g][kt]));
        }
#pragma unroll
        for (int kt = 0; kt < 4; kt++) {
            unsigned off = gc * HH + kt * 32 + kg * 8;
            Wi1[g][kt] = ldfrag(wih1, off, s);
            asm volatile("" : "+a"(Wi1[g][kt]));
        }
#pragma unroll
        for (int kt = 0; kt < 2; kt++) {
            unsigned off = gc * HH + kt * 32 + kg * 8;
            Whr[g][kt] = ldfrag(whh1, off, s);
            asm volatile("" : "+a"(Whr[g][kt]));
        }
    }

    const int jj  = nrow;
    const int rlo = kg;               // 0..3 ; cell rows rlo, rlo+4
    const int j   = 16 * wv + jj;
    float c0[2] = {0.f, 0.f};
    float c1[2] = {0.f, 0.f};
    __syncthreads();

    // per-wave volatile handoff views
    volatile float* gAv = &gA[wv][0][0][0];
    volatile float* gBv = &gB[wv][0][0][0];

    // ---- recurrence: ONE barrier per iteration ----
    for (int it = 0; it <= TT; it++) {
        const int p = (it + 1) & 1;   // buffer holding h0(it-1) / gets h1(it-1)
        const int q = it & 1;         // buffer for h0(it); holds h1(it-2)
        const bool doA = (it < TT);
        const bool doB = (it > 0);

        // x for cell0 (rows rlo, rlo+4) — issued early, L1-resident broadcast
        float xh[2], xg[2];
        if (doA) {
            unsigned gi0 = (unsigned)(b0 + rlo) * TT + it;
            unsigned gi1 = (unsigned)(b0 + rlo + 4) * TT + it;
            xh[0] = hr[gi0]; xh[1] = hr[gi1];
            xg[0] = glu[gi0]; xg[1] = glu[gi1];
        }
        // A-frags of h0(it-1) — shared by MM0 and MM1 part1
        short8 a0[4];
#pragma unroll
        for (int kt = 0; kt < 4; kt++)
            a0[kt] = *reinterpret_cast<const short8*>(&h0b[p][nrow][kt * 32 + kg * 8]);

        if (doA) {
            // MM0(it): gates0 = bias0 + h0(it-1) @ whh0^T
            f32x4 acc[4];
            {
                f32x4 bv = *reinterpret_cast<const f32x4*>(&b0t[j][0]);
#pragma unroll
                for (int g = 0; g < 4; g++) { float b = bv[g]; f32x4 z = {b, b, b, b}; acc[g] = z; }
            }
#pragma unroll
            for (int kt = 0; kt < 4; kt++)
#pragma unroll
                for (int g = 0; g < 4; g++)
                    acc[g] = MFMA(a0[kt], W0f[g][kt], acc[g]);
            // intra-wave handoff (C/D: col=lane&15, row=4*kg+rr) — VOLATILE
            if (kg < 2) {
#pragma unroll
                for (int g = 0; g < 4; g++)
#pragma unroll
                    for (int rr = 0; rr < 4; rr++)
                        gAv[(g * 8 + 4 * kg + rr) * 16 + nrow] = acc[g][rr];
            }
            __builtin_amdgcn_sched_barrier(0);   // machine-level pin
            // cell0(it): all 64 lanes, 2 units (rows rlo, rlo+4) of col j
            f32x4 w01 = *reinterpret_cast<const f32x4*>(&wab[j][0]); // wa0,wb0,wa1,wb1
            f32x4 w23 = *reinterpret_cast<const f32x4*>(&wab[j][4]); // wa2,wb2,wa3,wb3
#pragma unroll
            for (int rep = 0; rep < 2; rep++) {
                int r = rlo + 4 * rep;
                float pi = gAv[(0 * 8 + r) * 16 + jj] + xh[rep] * w01[0] + xg[rep] * w01[1];
                float pf = gAv[(1 * 8 + r) * 16 + jj] + xh[rep] * w01[2] + xg[rep] * w01[3];
                float pg = gAv[(2 * 8 + r) * 16 + jj] + xh[rep] * w23[0] + xg[rep] * w23[1];
                float po = gAv[(3 * 8 + r) * 16 + jj] + xh[rep] * w23[2] + xg[rep] * w23[3];
                float ig = sigm_s(pi), fg = sigm_s(pf), gg = tanh_s(pg), og = sigm_s(po);
                float c = fg * c0[rep] + ig * gg;
                c0[rep] = c;
                h0b[q][r][j] = f2b(og * tanh_c(c));   // h0(it) -> buf q
            }
        }
        if (doB) {
            // MM1(it-1): gates1 = bias1 + h0(it-1)@wih1^T + h1(it-2)@whh1^T
            f32x4 acc[4];
            short8 wf0[4], wf1[4];
            // prefetch streamed whh1 kt2 group (covered by 16 Wi1 MFMAs)
#pragma unroll
            for (int g = 0; g < 4; g++) wf0[g] = wtab[g][tid];
            {
                f32x4 bv = *reinterpret_cast<const f32x4*>(&b1t[j][0]);
#pragma unroll
                for (int g = 0; g < 4; g++) { float b = bv[g]; f32x4 z = {b, b, b, b}; acc[g] = z; }
            }
            // part1: h0(it-1) @ wih1^T (resident)
#pragma unroll
            for (int kt = 0; kt < 4; kt++)
#pragma unroll
                for (int g = 0; g < 4; g++)
                    acc[g] = MFMA(a0[kt], Wi1[g][kt], acc[g]);
            // prefetch kt3 group (covered by kt0-2 MFMAs below)
#pragma unroll
            for (int g = 0; g < 4; g++) wf1[g] = wtab[4 + g][tid];
            // part2: h1(it-2) @ whh1^T — kt0,1 resident; kt2,3 streamed
            {
                short8 a1;
                a1 = *reinterpret_cast<const short8*>(&h1b[q][nrow][0 * 32 + kg * 8]);
#pragma unroll
                for (int g = 0; g < 4; g++) acc[g] = MFMA(a1, Whr[g][0], acc[g]);
                a1 = *reinterpret_cast<const short8*>(&h1b[q][nrow][1 * 32 + kg * 8]);
#pragma unroll
                for (int g = 0; g < 4; g++) acc[g] = MFMA(a1, Whr[g][1], acc[g]);
                a1 = *reinterpret_cast<const short8*>(&h1b[q][nrow][2 * 32 + kg * 8]);
#pragma unroll
                for (int g = 0; g < 4; g++) acc[g] = MFMA(a1, wf0[g], acc[g]);
                a1 = *reinterpret_cast<const short8*>(&h1b[q][nrow][3 * 32 + kg * 8]);
#pragma unroll
                for (int g = 0; g < 4; g++) acc[g] = MFMA(a1, wf1[g], acc[g]);
            }
            if (kg < 2) {
#pragma unroll
                for (int g = 0; g < 4; g++)
#pragma unroll
                    for (int rr = 0; rr < 4; rr++)
                        gBv[(g * 8 + 4 * kg + rr) * 16 + nrow] = acc[g][rr];
            }
            __builtin_amdgcn_sched_barrier(0);
            // cell1(it-1): pre-activation complete (bias folded); h1 -> buf p
#pragma unroll
            for (int rep = 0; rep < 2; rep++) {
                int r = rlo + 4 * rep;
                float pi = gBv[(0 * 8 + r) * 16 + jj];
                float pf = gBv[(1 * 8 + r) * 16 + jj];
                float pg = gBv[(2 * 8 + r) * 16 + jj];
                float po = gBv[(3 * 8 + r) * 16 + jj];
                float ig = sigm_s(pi), fg = sigm_s(pf), gg = tanh_s(pg), og = sigm_s(po);
                float c = fg * c1[rep] + ig * gg;
                c1[rep] = c;
                h1b[p][r][j] = f2b(og * tanh_c(c));
            }
        }
        __syncthreads();
    }

    // ---- head: h1 final = h1(TT-1) in h1b[(TT+1)&1] = h1b[1] ----
    {
        int r  = tid >> 6;      // 0..7
        int ff = tid & 63;
        float a2 = 0.f;
        for (int k = 0; k < HH; k++)
            a2 += b2f(h1b[1][r][k]) * w1[(unsigned)ff * HH + k];
        hid[r][ff] = fmaxf(a2 + b1[ff], 0.f);
    }
    __syncthreads();
    if (tid < 16) {
        int r = tid >> 1;
        int o = tid & 1;
        float a2 = b2[o];
        for (int k = 0; k < FFD; k++)
            a2 += hid[r][k] * w2[(unsigned)o * FFD + k];
        out[(b0 + r) * 2 + o] = a2;    // fp32 output
    }
}

extern "C" void kernel_launch(void* const* d_in, const int* in_sizes, int n_in,
                              void* d_out, int out_size, void* d_ws, size_t ws_size,
                              hipStream_t stream) {
    const float* hr   = (const float*)d_in[0];
    const float* glu  = (const float*)d_in[1];
    const float* wih0 = (const float*)d_in[2];
    const float* whh0 = (const float*)d_in[3];
    const float* bih0 = (const float*)d_in[4];
    const float* bhh0 = (const float*)d_in[5];
    const float* wih1 = (const float*)d_in[6];
    const float* whh1 = (const float*)d_in[7];
    const float* bih1 = (const float*)d_in[8];
    const float* bhh1 = (const float*)d_in[9];
    const float* w1   = (const float*)d_in[10];
    const float* b1   = (const float*)d_in[11];
    const float* w2   = (const float*)d_in[12];
    const float* b2   = (const float*)d_in[13];
    float* out = (float*)d_out;

    lstm2_fused<<<dim3(2048 / BB), dim3(NT), 0, stream>>>(
        hr, glu, wih0, whh0, bih0, bhh0, wih1, whh1, bih1, bhh1,
        w1, b1, w2, b2, out);
}